// Round 7
// baseline (293.805 us; speedup 1.0000x reference)
//
#include <hip/hip_runtime.h>

#define DEPTH 128
#define GRPB 8   // graphs per pool block: 4096/8 = 512 blocks, ~2 MB contiguous each

typedef float f4 __attribute__((ext_vector_type(4)));

// Kernel 1: segment boundary search. batch is sorted; start[g] = first index
// with batch[i] >= g, for g in [0, G].
__global__ void find_starts_kernel(const int* __restrict__ batch,
                                   int* __restrict__ start, int N, int G) {
    int g = blockIdx.x * blockDim.x + threadIdx.x;
    if (g > G) return;
    int lo = 0, hi = N;
    while (lo < hi) {
        int mid = (lo + hi) >> 1;
        if (batch[mid] < g) lo = mid + 1; else hi = mid;
    }
    start[g] = lo;
}

// Kernel 2: 512 blocks x 256 threads. Each block owns GRPB consecutive graphs
// (one contiguous ~2 MB region) and processes them sequentially with R1's
// exact loop structure: 8 row-groups, 4-unroll, register sum/max, 8-row LDS
// reduce, fused per-graph MLP.
__global__ __launch_bounds__(256) void pool_mlp_kernel(
    const f4* __restrict__ x4, const int* __restrict__ start,
    const float* __restrict__ W1, const float* __restrict__ b1,
    const float* __restrict__ W2, const float* __restrict__ b2,
    float* __restrict__ out, int G)
{
    const int tid = threadIdx.x;
    const int rg  = tid >> 5;   // row group 0..7
    const int d4  = tid & 31;   // float4 column 0..31
    const int g0  = blockIdx.x * GRPB;

    __shared__ int sb[GRPB + 1];
    if (tid <= GRPB) sb[tid] = start[g0 + tid];
    __syncthreads();

    __shared__ f4 redS[8][32];
    __shared__ f4 redM[8][32];
    __shared__ float hbuf[3 * DEPTH];
    __shared__ float abuf[DEPTH];

#define ACC(v, s, m) do { \
        (s) += (v); \
        (m).x = fmaxf((m).x, (v).x); (m).y = fmaxf((m).y, (v).y); \
        (m).z = fmaxf((m).z, (v).z); (m).w = fmaxf((m).w, (v).w); } while (0)

    for (int gi = 0; gi < GRPB; ++gi) {
        const int s0 = sb[gi], s1 = sb[gi + 1];

        f4 sum0 = (f4)(0.f), sum1 = sum0, sum2 = sum0, sum3 = sum0;
        f4 mx0 = (f4)(-INFINITY), mx1 = mx0, mx2 = mx0, mx3 = mx0;

        int r = s0 + rg;
        for (; r + 24 < s1; r += 32) {
            f4 v0 = x4[(size_t)(r)      * 32 + d4];
            f4 v1 = x4[(size_t)(r + 8)  * 32 + d4];
            f4 v2 = x4[(size_t)(r + 16) * 32 + d4];
            f4 v3 = x4[(size_t)(r + 24) * 32 + d4];
            ACC(v0, sum0, mx0); ACC(v1, sum1, mx1);
            ACC(v2, sum2, mx2); ACC(v3, sum3, mx3);
        }
        for (; r < s1; r += 8) {
            f4 v = x4[(size_t)r * 32 + d4];
            ACC(v, sum0, mx0);
        }

        f4 sum = sum0 + sum1 + sum2 + sum3;
        f4 mx;
        mx.x = fmaxf(fmaxf(mx0.x, mx1.x), fmaxf(mx2.x, mx3.x));
        mx.y = fmaxf(fmaxf(mx0.y, mx1.y), fmaxf(mx2.y, mx3.y));
        mx.z = fmaxf(fmaxf(mx0.z, mx1.z), fmaxf(mx2.z, mx3.z));
        mx.w = fmaxf(fmaxf(mx0.w, mx1.w), fmaxf(mx2.w, mx3.w));

        redS[rg][d4] = sum;
        redM[rg][d4] = mx;
        __syncthreads();

        if (tid < 32) {
            f4 s = redS[0][d4];
            f4 m = redM[0][d4];
            #pragma unroll
            for (int i = 1; i < 8; ++i) {
                s += redS[i][d4];
                f4 tm = redM[i][d4];
                m.x = fmaxf(m.x, tm.x); m.y = fmaxf(m.y, tm.y);
                m.z = fmaxf(m.z, tm.z); m.w = fmaxf(m.w, tm.w);
            }
            const int cnt = s1 - s0;
            const float inv = 1.0f / (float)(cnt > 1 ? cnt : 1);
            if (cnt == 0) m = (f4)(0.f);
            const int d = d4 * 4;
            hbuf[d + 0] = m.x; hbuf[d + 1] = m.y; hbuf[d + 2] = m.z; hbuf[d + 3] = m.w;
            hbuf[DEPTH + d + 0] = s.x * inv; hbuf[DEPTH + d + 1] = s.y * inv;
            hbuf[DEPTH + d + 2] = s.z * inv; hbuf[DEPTH + d + 3] = s.w * inv;
            hbuf[2 * DEPTH + d + 0] = s.x; hbuf[2 * DEPTH + d + 1] = s.y;
            hbuf[2 * DEPTH + d + 2] = s.z; hbuf[2 * DEPTH + d + 3] = s.w;
        }
        __syncthreads();

        // Layer 1: abuf[j] = leaky_relu(b1[j] + hbuf . W1[j][:]), W1 is [128][384]
        if (tid < DEPTH) {
            float acc = b1[tid];
            const f4* w  = reinterpret_cast<const f4*>(W1 + (size_t)tid * 3 * DEPTH);
            const f4* h4 = reinterpret_cast<const f4*>(hbuf);
            #pragma unroll 8
            for (int k = 0; k < (3 * DEPTH) / 4; ++k) {
                f4 wv = w[k], hv = h4[k];
                acc += wv.x * hv.x + wv.y * hv.y + wv.z * hv.z + wv.w * hv.w;
            }
            abuf[tid] = (acc > 0.f) ? acc : 0.01f * acc;
        }
        __syncthreads();

        // Layer 2: out[g][j] = b2[j] + abuf . W2[j][:], W2 is [128][128]
        if (tid < DEPTH) {
            float acc = b2[tid];
            const f4* w  = reinterpret_cast<const f4*>(W2 + (size_t)tid * DEPTH);
            const f4* a4 = reinterpret_cast<const f4*>(abuf);
            #pragma unroll 8
            for (int k = 0; k < DEPTH / 4; ++k) {
                f4 wv = w[k], av = a4[k];
                acc += wv.x * av.x + wv.y * av.y + wv.z * av.z + wv.w * av.w;
            }
            out[(size_t)(g0 + gi) * DEPTH + tid] = acc;
        }
        __syncthreads();   // redS/redM/hbuf reused next graph
    }
#undef ACC
}

extern "C" void kernel_launch(void* const* d_in, const int* in_sizes, int n_in,
                              void* d_out, int out_size, void* d_ws, size_t ws_size,
                              hipStream_t stream) {
    const float* x     = (const float*)d_in[0];
    const int*   batch = (const int*)d_in[1];
    const float* W1 = (const float*)d_in[3];
    const float* b1 = (const float*)d_in[4];
    const float* W2 = (const float*)d_in[5];
    const float* b2 = (const float*)d_in[6];
    float* out = (float*)d_out;

    const int N = in_sizes[0] / DEPTH;   // 2,000,000 nodes
    const int G = out_size / DEPTH;      // 4096 graphs

    int* start = (int*)d_ws;             // G+1 ints, rewritten fully every call

    find_starts_kernel<<<(G + 256) / 256, 256, 0, stream>>>(batch, start, N, G);
    pool_mlp_kernel<<<G / GRPB, 256, 0, stream>>>(
        (const f4*)x, start, W1, b1, W2, b2, out, G);
}